// Round 11
// baseline (243.781 us; speedup 1.0000x reference)
//
#include <hip/hip_runtime.h>
#include <hip/hip_bf16.h>

// ModalAttention fused pipeline, MI355X (gfx950).
//
// Math: attn/|global_min| followed by L2-normalize cancels any positive
// per-tensor scale (incl. /sqrt(h)) -> softmax input = s_row/||s_row||_2,
// s = q.k. No global-min reduction needed.
//
// Round 11: qkv = fp8 e4m3 on the round-9 skeleton (best bf16 structure:
// 128x256 tile, ring-3 LDS, 2 blocks/CU, vmcnt(3)). BK=64 fp8 = two
// v_mfma_f32_16x16x32_fp8_fp8 K-steps per phase: 16 ds_read_b64 + 3
// staging loads per 32 MFMA (vs r9: 24 b128-equivalents per 16 MFMA).
// 8B-granule swizzle g ^= 2*((row>>1)&3): all 32 banks at the b64 minimum
// of 4 accesses/wave; stage-side involution identical to r5's verified
// per-lane constant. fp8 accuracy proven in r8 (absmax unchanged 0.03125).
// All other kernels identical to round-10 passing code.

typedef __bf16 bf16x8 __attribute__((ext_vector_type(8)));
typedef float f32x4 __attribute__((ext_vector_type(4)));

struct alignas(16) US8 { unsigned short s[8]; };
struct alignas(8)  US4 { unsigned short s[4]; };

// ---------------- workspace layout (bytes) ----------------
#define WS_XB   0ull                        // data bf16 [16384][1024] 33.55MB (ln residual)
#define WS_XF8  33554432ull                 // data fp8  [16384][1024] 16.78MB
#define WS_WF8  50331648ull                 // wq,wk,wv fp8 [3][1024][1024] 3.15MB
#define WS_Q    53477376ull                 // Q bf16 [16384][1024] 33.55MB
#define WS_K    87031808ull                 // K bf16 [16384][1024] 33.55MB
#define WS_VT   120586240ull                // V^T bf16 [32][1024][512] 33.55MB
#define WS_S    154140672ull                // S bf16 [16384][512] 16.78MB
#define WS_P    170917888ull                // P bf16 [16384][512] 16.78MB
#define WS_NEED 187695104ull
#define WS_O    WS_Q                        // O bf16 reuses Q (dead after s_gemm)

__device__ __forceinline__ unsigned short f32_to_bf16(float f) {
  unsigned int u = __builtin_bit_cast(unsigned int, f);
  u += 0x7fffu + ((u >> 16) & 1u);            // round-to-nearest-even
  return (unsigned short)(u >> 16);
}
__device__ __forceinline__ float bf16_to_f32(unsigned short h) {
  return __builtin_bit_cast(float, (unsigned int)h << 16);
}

__device__ __forceinline__ void gload_lds16(const void* g, void* lds) {
  __builtin_amdgcn_global_load_lds(
      (const __attribute__((address_space(1))) unsigned int*)g,
      (__attribute__((address_space(3))) unsigned int*)lds, 16, 0, 0);
}

__device__ __forceinline__ float wave_sum(float v) {
#pragma unroll
  for (int off = 32; off > 0; off >>= 1) v += __shfl_xor(v, off);
  return v;
}
__device__ __forceinline__ float wave_max(float v) {
#pragma unroll
  for (int off = 32; off > 0; off >>= 1) v = fmaxf(v, __shfl_xor(v, off));
  return v;
}

__device__ __forceinline__ unsigned int pk_fp8x4(float a, float b, float c, float d) {
  unsigned int v = 0;
  v = __builtin_amdgcn_cvt_pk_fp8_f32(a, b, v, false);  // bytes 0,1
  v = __builtin_amdgcn_cvt_pk_fp8_f32(c, d, v, true);   // bytes 2,3
  return v;
}

// ---------------- data cast: f32 -> bf16 (Xb) + fp8 (Xf8) ----------------
__global__ __launch_bounds__(256) void cvt_data(const float* __restrict__ src,
                                                unsigned short* __restrict__ dstb,
                                                unsigned int* __restrict__ dst8,
                                                int n8) {
  int i = blockIdx.x * 256 + threadIdx.x;
  if (i >= n8) return;
  const float4* sp = (const float4*)(src + (size_t)i * 8);
  float4 a = sp[0], b = sp[1];
  US8 u;
  u.s[0] = f32_to_bf16(a.x); u.s[1] = f32_to_bf16(a.y);
  u.s[2] = f32_to_bf16(a.z); u.s[3] = f32_to_bf16(a.w);
  u.s[4] = f32_to_bf16(b.x); u.s[5] = f32_to_bf16(b.y);
  u.s[6] = f32_to_bf16(b.z); u.s[7] = f32_to_bf16(b.w);
  *(US8*)(dstb + (size_t)i * 8) = u;
  uint2 w;
  w.x = pk_fp8x4(a.x, a.y, a.z, a.w);
  w.y = pk_fp8x4(b.x, b.y, b.z, b.w);
  *(uint2*)(dst8 + (size_t)i * 2) = w;
}

// ---------------- weights cast: f32 -> fp8, 3 matrices, one launch -------
__global__ __launch_bounds__(256) void cvt_w3(const float* __restrict__ wq,
                                              const float* __restrict__ wk,
                                              const float* __restrict__ wv,
                                              unsigned int* __restrict__ dst8) {
  const int z = blockIdx.y;
  const float* src = (z == 0) ? wq : (z == 1) ? wk : wv;
  int i = blockIdx.x * 256 + threadIdx.x;   // 0..131071 (x8 elems)
  const float4* sp = (const float4*)(src + (size_t)i * 8);
  float4 a = sp[0], b = sp[1];
  uint2 w;
  w.x = pk_fp8x4(a.x, a.y, a.z, a.w);
  w.y = pk_fp8x4(b.x, b.y, b.z, b.w);
  *(uint2*)(dst8 + (size_t)z * 262144 + (size_t)i * 2) = w;
}

// ============ QKV fp8: 128x256 tile, ring-3 BK=64, N=3072, 2 blk/CU =======
// M=16384 -> 128 M-tiles; N=3072 -> 12 N-tiles; grid 1536 x 512 thr (8 waves,
// wm = w>>2 in {0,1} = 64-row half, wn = w&3 = 64-col quarter; per-wave 64x64,
// acc[4][4] = 64 AGPR). K=1024 = 16 subtiles of 64 fp8.
// LDS slot (24KB): A[128][64B] @0, B[256][64B] @8192. Ring-3 = 72KB.
// Swizzle (8B granules, 16B-pair-preserving): chunk' = chunk ^ ((row>>1)&3).
__global__ __launch_bounds__(512, 4) void qkv_f8(
    const unsigned char* __restrict__ Xf8, const unsigned char* __restrict__ Wf8,
    unsigned short* __restrict__ Q, unsigned short* __restrict__ Kb,
    unsigned short* __restrict__ Vt) {
  __shared__ char smc[3][24576];

  const int tid = threadIdx.x;
  const int w = tid >> 6, lane = tid & 63;
  const int wm = w >> 2, wn = w & 3;
  const int lr = lane & 15, lk4 = lane >> 4;

  // bijective XCD-chunked swizzle: 1536 blocks, 192 per XCD
  const int bid = blockIdx.x;
  const int wg = (bid & 7) * 192 + (bid >> 3);
  const int bm = wg / 12, bn = wg % 12;

  const char* Ag = (const char*)Xf8 + (size_t)bm * 128 * 1024;
  const char* Bg = (const char*)Wf8 + (size_t)bn * 256 * 1024;

  // stage: dest byte = region + tid*16 -> row = tid>>2, chunk = tid&3;
  // src chunk = (tid&3) ^ ((row>>1)&3) = (tid&3) ^ ((tid>>3)&3)
  const int srow = tid >> 2;                        // 0..127
  const int sch  = ((tid & 3) ^ ((tid >> 3) & 3)) * 16;
  const char* pA  = Ag + (size_t)srow * 1024 + sch;
  const char* pB0 = Bg + (size_t)srow * 1024 + sch;
  const char* pB1 = pB0 + 128 * 1024;               // rows 128..255 (x=same)

  // read: row = base + lr (bases 0 mod 16); want src chunk (2*ks + (lk4>>1)),
  // half (lk4&1) -> LDS byte = ((2*ks + (lk4>>1)) ^ ((lr>>1)&3))*16 + (lk4&1)*8
  const int xr = (lr >> 1) & 3;
  const int cA0 = (((lk4 >> 1) ^ xr) * 16) + (lk4 & 1) * 8;   // ks=0; ks=1 = ^32
  const int rowA = wm * 64 + lr;    // + m*16, rows 0..127
  const int rowB = wn * 64 + lr;    // + n*16, rows 0..255

  f32x4 acc[4][4] = {};

#define QKV_STAGE3(SI)                                                        \
  do {                                                                        \
    char* dd = (char*)smc[SI];                                                \
    gload_lds16(pA,  dd + tid * 16);                                          \
    gload_lds16(pB0, dd + 8192 + tid * 16);                                   \
    gload_lds16(pB1, dd + 16384 + tid * 16);                                  \
    pA += 64; pB0 += 64; pB1 += 64;                                           \
  } while (0)

#define MFMA8(AV, BV)                                                         \
  asm("v_mfma_f32_16x16x32_fp8_fp8 %0, %1, %2, %0"                            \
      : "+a"(acc[mq][nq]) : "v"(AV), "v"(BV))

#define QKV_PHASE(SLOT, VM, DO_STAGE)                                         \
  do {                                                                        \
    asm volatile("s_waitcnt vmcnt(" #VM ")" ::: "memory");                    \
    __builtin_amdgcn_s_barrier();                                             \
    __builtin_amdgcn_sched_barrier(0);                                        \
    const char* sA = (const char*)smc[SLOT];                                  \
    const char* sB = sA + 8192;                                               \
    long av0[4], av1[4], bv0[4], bv1[4];                                      \
    _Pragma("unroll") for (int m = 0; m < 4; ++m) {                           \
      av0[m] = *(const long*)(sA + (rowA + m * 16) * 64 + cA0);               \
      av1[m] = *(const long*)(sA + (rowA + m * 16) * 64 + (cA0 ^ 32));        \
    }                                                                         \
    _Pragma("unroll") for (int n = 0; n < 4; ++n) {                           \
      bv0[n] = *(const long*)(sB + (rowB + n * 16) * 64 + cA0);               \
      bv1[n] = *(const long*)(sB + (rowB + n * 16) * 64 + (cA0 ^ 32));        \
    }                                                                         \
    if (DO_STAGE) QKV_STAGE3((SLOT + 2) % 3);                                 \
    __builtin_amdgcn_s_setprio(1);                                            \
    _Pragma("unroll") for (int mq = 0; mq < 4; ++mq)                          \
        _Pragma("unroll") for (int nq = 0; nq < 4; ++nq)                      \
            MFMA8(av0[mq], bv0[nq]);                                          \
    _Pragma("unroll") for (int mq = 0; mq < 4; ++mq)                          \
        _Pragma("unroll") for (int nq = 0; nq < 4; ++nq)                      \
            MFMA8(av1[mq], bv1[nq]);                                          \
    __builtin_amdgcn_s_setprio(0);                                            \
    __builtin_amdgcn_sched_barrier(0);                                        \
  } while (0)

  // prologue: stage subtiles 0,1 into slots 0,1 (6 loads/thread in flight)
  QKV_STAGE3(0);
  QKV_STAGE3(1);

  // phases s=0..11 (4 iters x 3), each stages subtile s+2 into (s+2)%3
  for (int i = 0; i < 4; ++i) {
    QKV_PHASE(0, 3, 1);
    QKV_PHASE(1, 3, 1);
    QKV_PHASE(2, 3, 1);
  }
  QKV_PHASE(0, 3, 1);   // s=12 stages 14
  QKV_PHASE(1, 3, 1);   // s=13 stages 15
  QKV_PHASE(2, 3, 0);   // s=14
  QKV_PHASE(0, 0, 0);   // s=15

#undef QKV_PHASE
#undef MFMA8
#undef QKV_STAGE3

  // epilogue: C fragment (row = base + (lane>>4)*4 + i, col = base + (lane&15))
  const int cr = lk4 << 2;
  const int z = bn >> 2;                       // 0=Q 1=K 2=V
  const int gr0 = bm * 128 + wm * 64;
  const int gc0 = (bn & 3) * 256 + wn * 64;
  if (z < 2) {
    unsigned short* C = (z == 0) ? Q : Kb;
#pragma unroll
    for (int m = 0; m < 4; ++m)
#pragma unroll
      for (int n = 0; n < 4; ++n)
#pragma unroll
        for (int i = 0; i < 4; ++i)
          C[(size_t)(gr0 + m * 16 + cr + i) * 1024 + (gc0 + n * 16 + lr)] =
              f32_to_bf16(acc[m][n][i]);
  } else {
    // Vt[b][d][t] = V[b*512+t][d]; 4 consecutive t per lane -> 8B store
#pragma unroll
    for (int m = 0; m < 4; ++m) {
      const int gr = gr0 + m * 16 + cr;
      const int b = gr >> 9, tt = gr & 511;
#pragma unroll
      for (int n = 0; n < 4; ++n) {
        const int d = gc0 + n * 16 + lr;
        US4 u;
        u.s[0] = f32_to_bf16(acc[m][n][0]);
        u.s[1] = f32_to_bf16(acc[m][n][1]);
        u.s[2] = f32_to_bf16(acc[m][n][2]);
        u.s[3] = f32_to_bf16(acc[m][n][3]);
        *(US4*)(Vt + ((size_t)b * 1024 + d) * 512 + tt) = u;
      }
    }
  }
}

// ---------------- shared BT-GEMM core (m97 structure + XOR swizzle) ----------
__device__ __forceinline__ void gemm_bt_core(const unsigned short* __restrict__ A,
                                             const unsigned short* __restrict__ B,
                                             int lda, int ldb, int K,
                                             unsigned short* As, unsigned short* Bs,
                                             f32x4 acc[4][4]) {
  const int tid = threadIdx.x;
  const int w = tid >> 6, lane = tid & 63;
  const int wr = w >> 1, wc = w & 1;
  const int lr = lane & 15;
  const int lk = (((lane >> 4) ^ ((lr >> 1) & 3))) << 3;
  const int k8 = (((lane & 3) ^ ((lane >> 3) & 3))) << 3;

  for (int kk = 0; kk < K; kk += 32) {
#pragma unroll
    for (int j = 0; j < 2; ++j) {
      const int i = (w << 1) + j;            // 0..7 wave-load id
      const int c = (i << 6) + lane;         // 16B chunk id, 512 per tile
      const int r = c >> 2;                  // tile row 0..127
      gload_lds16(A + (size_t)r * lda + kk + k8, As + (i << 9));
      gload_lds16(B + (size_t)r * ldb + kk + k8, Bs + (i << 9));
    }
    __syncthreads();                         // drains vmcnt for all waves
    bf16x8 av[4], bv[4];
#pragma unroll
    for (int m = 0; m < 4; ++m)
      av[m] = *(const bf16x8*)(As + (((wr << 6) + (m << 4) + lr) << 5) + lk);
#pragma unroll
    for (int n = 0; n < 4; ++n)
      bv[n] = *(const bf16x8*)(Bs + (((wc << 6) + (n << 4) + lr) << 5) + lk);
#pragma unroll
    for (int m = 0; m < 4; ++m)
#pragma unroll
      for (int n = 0; n < 4; ++n)
        acc[m][n] = __builtin_amdgcn_mfma_f32_16x16x32_bf16(av[m], bv[n], acc[m][n], 0, 0, 0);
    __syncthreads();
  }
}

// ---------------- S = Q K^T per batch (bf16 out) ----------------
__global__ __launch_bounds__(256) void s_gemm(const unsigned short* __restrict__ Q,
                                              const unsigned short* __restrict__ Kb,
                                              unsigned short* __restrict__ S) {
  __shared__ unsigned short As[4096];
  __shared__ unsigned short Bs[4096];
  const int bn = blockIdx.x, bm = blockIdx.y, b = blockIdx.z;
  const unsigned short* A = Q + ((size_t)b * 512 + bm * 128) * 1024;
  const unsigned short* B = Kb + ((size_t)b * 512 + bn * 128) * 1024;
  f32x4 acc[4][4] = {};
  gemm_bt_core(A, B, 1024, 1024, 1024, As, Bs, acc);

  const int tid = threadIdx.x;
  const int w = tid >> 6, lane = tid & 63;
  const int wr = w >> 1, wc = w & 1;
  const int cr = (lane >> 4) << 2;
  const int cc = lane & 15;
  unsigned short* Cp = S + (size_t)b * 262144;
  const int rbase = bm * 128 + wr * 64;
  const int cbase = bn * 128 + wc * 64;
#pragma unroll
  for (int m = 0; m < 4; ++m)
#pragma unroll
    for (int n = 0; n < 4; ++n)
#pragma unroll
      for (int i = 0; i < 4; ++i)
        Cp[(size_t)(rbase + m * 16 + cr + i) * 512 + (cbase + n * 16 + cc)] =
            f32_to_bf16(acc[m][n][i]);
}

// ---------------- row L2-normalize + softmax; write attn f32 + P bf16 -------
__global__ __launch_bounds__(256) void softmax_rows(const unsigned short* __restrict__ S,
                                                    float* __restrict__ out,
                                                    unsigned short* __restrict__ P) {
  const int w = threadIdx.x >> 6, lane = threadIdx.x & 63;
  const int r = blockIdx.x * 4 + w;          // global row 0..16383
  const int b = r >> 9, s = r & 511;
  US8 v = *(const US8*)(S + (size_t)r * 512 + lane * 8);
  float x[8];
#pragma unroll
  for (int i = 0; i < 8; ++i) x[i] = bf16_to_f32(v.s[i]);
  float ss = 0.f;
#pragma unroll
  for (int i = 0; i < 8; ++i) ss += x[i] * x[i];
  ss = wave_sum(ss);
  const float inv = 1.0f / fmaxf(sqrtf(ss), 1e-12f);
  float mx = -1e30f;
#pragma unroll
  for (int i = 0; i < 8; ++i) { x[i] *= inv; mx = fmaxf(mx, x[i]); }
  mx = wave_max(mx);
  float se = 0.f;
#pragma unroll
  for (int i = 0; i < 8; ++i) { x[i] = __expf(x[i] - mx); se += x[i]; }
  se = wave_sum(se);
  const float rs = 1.0f / se;
#pragma unroll
  for (int i = 0; i < 8; ++i) x[i] *= rs;

  float* op = out + (size_t)b * 786432 + 524288 + (size_t)s * 512 + lane * 8;
  float4 o0 = {x[0], x[1], x[2], x[3]};
  float4 o1 = {x[4], x[5], x[6], x[7]};
  *(float4*)op = o0;
  *(float4*)(op + 4) = o1;
  US8 u;
#pragma unroll
  for (int i = 0; i < 8; ++i) u.s[i] = f32_to_bf16(x[i]);
  *(US8*)(P + (size_t)r * 512 + lane * 8) = u;
}

// ---------------- O = P * V (via Vt, BT layout), bf16 out ----------------
__global__ __launch_bounds__(256) void pv_gemm(const unsigned short* __restrict__ P,
                                               const unsigned short* __restrict__ Vt,
                                               unsigned short* __restrict__ O) {
  __shared__ unsigned short As[4096];
  __shared__ unsigned short Bs[4096];
  const int bn = blockIdx.x, bm = blockIdx.y, b = blockIdx.z;
  const unsigned short* A = P + ((size_t)b * 512 + bm * 128) * 512;
  const unsigned short* B = Vt + ((size_t)b * 1024 + bn * 128) * 512;
  f32x4 acc[4][4] = {};
  gemm_bt_core(A, B, 512, 512, 512, As, Bs, acc);

  const int tid = threadIdx.x;
  const int w = tid >> 6, lane = tid & 63;
  const int wr = w >> 1, wc = w & 1;
  const int cr = (lane >> 4) << 2;
  const int cc = lane & 15;
  const int grow = b * 512 + bm * 128 + wr * 64;
  const int cbase = bn * 128 + wc * 64;
#pragma unroll
  for (int m = 0; m < 4; ++m)
#pragma unroll
    for (int n = 0; n < 4; ++n)
#pragma unroll
      for (int i = 0; i < 4; ++i)
        O[(size_t)(grow + m * 16 + cr + i) * 1024 + (cbase + n * 16 + cc)] =
            f32_to_bf16(acc[m][n][i]);
}

// ---------------- residual + LayerNorm, wave per row ----------------
__global__ __launch_bounds__(256) void ln_rows(const unsigned short* __restrict__ O,
                                               const unsigned short* __restrict__ Xb,
                                               const float* __restrict__ gamma,
                                               const float* __restrict__ beta,
                                               float* __restrict__ out) {
  const int w = threadIdx.x >> 6, lane = threadIdx.x & 63;
  const int r = blockIdx.x * 4 + w;
  const int b = r >> 9, s = r & 511;
  const unsigned short* orow = O + (size_t)r * 1024;
  const unsigned short* drow = Xb + (size_t)r * 1024;
  float x[16];
  float sm = 0.f, sq = 0.f;
#pragma unroll
  for (int j = 0; j < 4; ++j) {
    const int col = j * 256 + lane * 4;
    US4 o4 = *(const US4*)(orow + col);
    US4 d4 = *(const US4*)(drow + col);
    x[j * 4 + 0] = bf16_to_f32(o4.s[0]) + bf16_to_f32(d4.s[0]);
    x[j * 4 + 1] = bf16_to_f32(o4.s[1]) + bf16_to_f32(d4.s[1]);
    x[j * 4 + 2] = bf16_to_f32(o4.s[2]) + bf16_to_f32(d4.s[2]);
    x[j * 4 + 3] = bf16_to_f32(o4.s[3]) + bf16_to_f32(d4.s[3]);
  }
#pragma unroll
  for (int i = 0; i < 16; ++i) { sm += x[i]; sq += x[i] * x[i]; }
  sm = wave_sum(sm);
  sq = wave_sum(sq);
  const float mean = sm * (1.0f / 1024.0f);
  const float var = sq * (1.0f / 1024.0f) - mean * mean;
  const float rstd = rsqrtf(var + 1e-6f);
  float* op = out + (size_t)b * 786432 + (size_t)s * 1024;
#pragma unroll
  for (int j = 0; j < 4; ++j) {
    const int col = j * 256 + lane * 4;
    float4 g4 = *(const float4*)(gamma + col);
    float4 b4 = *(const float4*)(beta + col);
    float4 y;
    y.x = (x[j * 4 + 0] - mean) * rstd * g4.x + b4.x;
    y.y = (x[j * 4 + 1] - mean) * rstd * g4.y + b4.y;
    y.z = (x[j * 4 + 2] - mean) * rstd * g4.z + b4.z;
    y.w = (x[j * 4 + 3] - mean) * rstd * g4.w + b4.w;
    *(float4*)(op + col) = y;
  }
}

extern "C" void kernel_launch(void* const* d_in, const int* in_sizes, int n_in,
                              void* d_out, int out_size, void* d_ws, size_t ws_size,
                              hipStream_t stream) {
  const float* data  = (const float*)d_in[0];
  const float* wq    = (const float*)d_in[1];
  const float* wk    = (const float*)d_in[2];
  const float* wv    = (const float*)d_in[3];
  const float* gamma = (const float*)d_in[4];
  const float* beta  = (const float*)d_in[5];
  float* out = (float*)d_out;
  char* ws = (char*)d_ws;
  if (ws_size < WS_NEED) return;

  unsigned short* Xb = (unsigned short*)(ws + WS_XB);
  unsigned int*  Xf8 = (unsigned int*)(ws + WS_XF8);
  unsigned int*  Wf8 = (unsigned int*)(ws + WS_WF8);
  unsigned short* Q  = (unsigned short*)(ws + WS_Q);
  unsigned short* Kb = (unsigned short*)(ws + WS_K);
  unsigned short* Vt = (unsigned short*)(ws + WS_VT);
  unsigned short* S  = (unsigned short*)(ws + WS_S);
  unsigned short* P  = (unsigned short*)(ws + WS_P);
  unsigned short* O  = (unsigned short*)(ws + WS_O);

  cvt_data<<<8192, 256, 0, stream>>>(data, Xb, Xf8, 2097152);
  cvt_w3<<<dim3(512, 3), 256, 0, stream>>>(wq, wk, wv, Wf8);
  qkv_f8<<<1536, 512, 0, stream>>>((const unsigned char*)Xf8,
                                   (const unsigned char*)Wf8, Q, Kb, Vt);
  s_gemm<<<dim3(4, 4, 32), 256, 0, stream>>>(Q, Kb, S);
  softmax_rows<<<4096, 256, 0, stream>>>(S, out, P);
  pv_gemm<<<dim3(8, 4, 32), 256, 0, stream>>>(P, Vt, O);
  ln_rows<<<4096, 256, 0, stream>>>(O, Xb, gamma, beta, out);
}

// Round 12
// 218.959 us; speedup vs baseline: 1.1134x; 1.1134x over previous
//
#include <hip/hip_runtime.h>
#include <hip/hip_bf16.h>

// ModalAttention fused pipeline, MI355X (gfx950).
//
// Math: attn/|global_min| followed by L2-normalize cancels any positive
// per-tensor scale (incl. /sqrt(h)) -> softmax input = s_row/||s_row||_2,
// s = q.k. No global-min reduction needed.
//
// Round 12: qkv = fp8 e4m3 with v_mfma_f32_16x16x128_f8f6f4 (mapping
// correctness-proven in r8), rebuilt without r8/r11's defects:
//  - (512,2) launch bounds -> 256-reg budget; acc only 64 AGPR (per-wave
//    64x64) + ~90 arch VGPR: no spill (r11 spilled at the 128 budget).
//  - K=128 rows stored as TWO 64B-row panels (k0-63 | k64-127): every
//    ds_read uses the r5/r9 formula (chunk ^ ((row>>1)&3) on 64B rows)
//    that measured 0 bank conflicts; bank multiset identical.
//  - r9's ring discipline: 2-slot (2x48KB), 6 staging loads/thread per
//    K-tile, counted vmcnt(6), two barriers/phase, setprio MFMA batches.
// Tile 128x256, grid 1536, 8 waves. Everything else = round-11 passing code.

typedef __bf16 bf16x8 __attribute__((ext_vector_type(8)));
typedef float f32x4 __attribute__((ext_vector_type(4)));
typedef int i32x4v __attribute__((ext_vector_type(4)));
typedef int i32x8v __attribute__((ext_vector_type(8)));

struct alignas(16) US8 { unsigned short s[8]; };
struct alignas(8)  US4 { unsigned short s[4]; };

// ---------------- workspace layout (bytes) ----------------
#define WS_XB   0ull                        // data bf16 [16384][1024] 33.55MB (ln residual)
#define WS_XF8  33554432ull                 // data fp8  [16384][1024] 16.78MB
#define WS_WF8  50331648ull                 // wq,wk,wv fp8 [3][1024][1024] 3.15MB
#define WS_Q    53477376ull                 // Q bf16 [16384][1024] 33.55MB
#define WS_K    87031808ull                 // K bf16 [16384][1024] 33.55MB
#define WS_VT   120586240ull                // V^T bf16 [32][1024][512] 33.55MB
#define WS_S    154140672ull                // S bf16 [16384][512] 16.78MB
#define WS_P    170917888ull                // P bf16 [16384][512] 16.78MB
#define WS_NEED 187695104ull
#define WS_O    WS_Q                        // O bf16 reuses Q (dead after s_gemm)

__device__ __forceinline__ unsigned short f32_to_bf16(float f) {
  unsigned int u = __builtin_bit_cast(unsigned int, f);
  u += 0x7fffu + ((u >> 16) & 1u);            // round-to-nearest-even
  return (unsigned short)(u >> 16);
}
__device__ __forceinline__ float bf16_to_f32(unsigned short h) {
  return __builtin_bit_cast(float, (unsigned int)h << 16);
}

__device__ __forceinline__ void gload_lds16(const void* g, void* lds) {
  __builtin_amdgcn_global_load_lds(
      (const __attribute__((address_space(1))) unsigned int*)g,
      (__attribute__((address_space(3))) unsigned int*)lds, 16, 0, 0);
}

__device__ __forceinline__ float wave_sum(float v) {
#pragma unroll
  for (int off = 32; off > 0; off >>= 1) v += __shfl_xor(v, off);
  return v;
}
__device__ __forceinline__ float wave_max(float v) {
#pragma unroll
  for (int off = 32; off > 0; off >>= 1) v = fmaxf(v, __shfl_xor(v, off));
  return v;
}

__device__ __forceinline__ unsigned int pk_fp8x4(float a, float b, float c, float d) {
  unsigned int v = 0;
  v = __builtin_amdgcn_cvt_pk_fp8_f32(a, b, v, false);  // bytes 0,1
  v = __builtin_amdgcn_cvt_pk_fp8_f32(c, d, v, true);   // bytes 2,3
  return v;
}

// ---------------- data cast: f32 -> bf16 (Xb) + fp8 (Xf8) ----------------
__global__ __launch_bounds__(256) void cvt_data(const float* __restrict__ src,
                                                unsigned short* __restrict__ dstb,
                                                unsigned int* __restrict__ dst8,
                                                int n8) {
  int i = blockIdx.x * 256 + threadIdx.x;
  if (i >= n8) return;
  const float4* sp = (const float4*)(src + (size_t)i * 8);
  float4 a = sp[0], b = sp[1];
  US8 u;
  u.s[0] = f32_to_bf16(a.x); u.s[1] = f32_to_bf16(a.y);
  u.s[2] = f32_to_bf16(a.z); u.s[3] = f32_to_bf16(a.w);
  u.s[4] = f32_to_bf16(b.x); u.s[5] = f32_to_bf16(b.y);
  u.s[6] = f32_to_bf16(b.z); u.s[7] = f32_to_bf16(b.w);
  *(US8*)(dstb + (size_t)i * 8) = u;
  uint2 w;
  w.x = pk_fp8x4(a.x, a.y, a.z, a.w);
  w.y = pk_fp8x4(b.x, b.y, b.z, b.w);
  *(uint2*)(dst8 + (size_t)i * 2) = w;
}

// ---------------- weights cast: f32 -> fp8, 3 matrices, one launch -------
__global__ __launch_bounds__(256) void cvt_w3(const float* __restrict__ wq,
                                              const float* __restrict__ wk,
                                              const float* __restrict__ wv,
                                              unsigned int* __restrict__ dst8) {
  const int z = blockIdx.y;
  const float* src = (z == 0) ? wq : (z == 1) ? wk : wv;
  int i = blockIdx.x * 256 + threadIdx.x;   // 0..131071 (x8 elems)
  const float4* sp = (const float4*)(src + (size_t)i * 8);
  float4 a = sp[0], b = sp[1];
  uint2 w;
  w.x = pk_fp8x4(a.x, a.y, a.z, a.w);
  w.y = pk_fp8x4(b.x, b.y, b.z, b.w);
  *(uint2*)(dst8 + (size_t)z * 262144 + (size_t)i * 2) = w;
}

// ============ QKV fp8 K=128: 128x256 tile, 2-slot, N=3072 ============
// M=16384 -> 128 M-tiles; N=3072 -> 12 N-tiles; grid 1536 x 512 thr
// (8 waves: wm=w>>2 row-half of 64, wn=w&3 col-quarter of 64).
// K=1024 = 8 K-tiles of 128. LDS slot (48KB):
//   A p0 [0,8K) rows128 x 64B (k0-63) | A p1 [8K,16K) (k64-127)
//   B p0 [16K,32K) rows256 x 64B      | B p1 [32K,48K)
// All reads use the r5/r9-verified 64B-row swizzle chunk^((row>>1)&3).
__global__ __launch_bounds__(512, 2) void qkv_k128(
    const unsigned char* __restrict__ Xf8, const unsigned char* __restrict__ Wf8,
    unsigned short* __restrict__ Q, unsigned short* __restrict__ Kb,
    unsigned short* __restrict__ Vt) {
  __shared__ alignas(16) char smc[2][49152];

  const int tid = threadIdx.x;
  const int w = tid >> 6, lane = tid & 63;
  const int wm = w >> 2, wn = w & 3;
  const int lr = lane & 15, lk4 = lane >> 4;

  // bijective XCD-chunked swizzle: 1536 blocks, 192 per XCD
  const int bid = blockIdx.x;
  const int wg = (bid & 7) * 192 + (bid >> 3);
  const int bm = wg / 12, bn = wg % 12;

  const char* Ag = (const char*)Xf8 + (size_t)bm * 128 * 1024;
  const char* Bg = (const char*)Wf8 + (size_t)bn * 256 * 1024;

  // stage: thread t -> dest chunk t of each 8KB region (row=t>>2, chunk=t&3);
  // src chunk = (t&3) ^ ((row>>1)&3) = (t&3) ^ ((t>>3)&3)  (per-lane const)
  const int sc = ((tid & 3) ^ ((tid >> 3) & 3)) * 16;
  const char* pA = Ag + (size_t)(tid >> 2) * 1024 + sc;   // +=128 per K-tile
  const char* pB = Bg + (size_t)(tid >> 2) * 1024 + sc;

  // read: lane k-range = lk4*32..+31 (r8-proven) -> panel lk4>>1,
  // in-panel chunks c0=(lk4&1)*2 and c0+1, swizzled by (lr>>1)&3.
  const int swz = (lr >> 1) & 3;
  const int c0 = (lk4 & 1) * 2;
  const int cb0 = ((c0) ^ swz) * 16;
  const int cb1 = ((c0 + 1) ^ swz) * 16;
  const int panA = (lk4 >> 1) * 8192;
  const int panB = 16384 + (lk4 >> 1) * 16384;
  const int rowA = (wm * 64 + lr) * 64;   // + m*1024
  const int rowB = (wn * 64 + lr) * 64;   // + n*1024

  f32x4 acc[4][4] = {};

#define STAGE6(SI)                                                            \
  do {                                                                        \
    char* dd = (char*)smc[SI];                                                \
    gload_lds16(pA,               dd + tid * 16);                             \
    gload_lds16(pA + 64,          dd + 8192 + tid * 16);                      \
    gload_lds16(pB,               dd + 16384 + tid * 16);                     \
    gload_lds16(pB + 131072,      dd + 24576 + tid * 16);                     \
    gload_lds16(pB + 64,          dd + 32768 + tid * 16);                     \
    gload_lds16(pB + 131072 + 64, dd + 40960 + tid * 16);                     \
    pA += 128; pB += 128;                                                     \
  } while (0)

#define MK8(D, OFF)                                                           \
  do {                                                                        \
    i32x4v lo_ = *(const i32x4v*)(sp + (OFF) + cb0);                          \
    i32x4v hi_ = *(const i32x4v*)(sp + (OFF) + cb1);                          \
    D[0] = lo_[0]; D[1] = lo_[1]; D[2] = lo_[2]; D[3] = lo_[3];               \
    D[4] = hi_[0]; D[5] = hi_[1]; D[6] = hi_[2]; D[7] = hi_[3];               \
  } while (0)

#define MFMA128(ACC, AV, BV)                                                  \
  asm("v_mfma_f32_16x16x128_f8f6f4 %0, %1, %2, %0"                            \
      : "+a"(ACC) : "v"(AV), "v"(BV))

#define QKV_PHASE(SLOT, VM, DO_STAGE)                                         \
  do {                                                                        \
    if (DO_STAGE) STAGE6((SLOT) ^ 1);                                         \
    asm volatile("s_waitcnt vmcnt(" #VM ")" ::: "memory");                    \
    __builtin_amdgcn_s_barrier();                                             \
    __builtin_amdgcn_sched_barrier(0);                                        \
    const char* sp = (const char*)smc[SLOT];                                  \
    i32x8v a0, a1, b0, b1, b2, b3;                                            \
    MK8(a0, panA + rowA);          MK8(a1, panA + rowA + 1024);               \
    MK8(b0, panB + rowB);          MK8(b1, panB + rowB + 1024);               \
    MK8(b2, panB + rowB + 2048);   MK8(b3, panB + rowB + 3072);               \
    __builtin_amdgcn_s_setprio(1);                                            \
    MFMA128(acc[0][0], a0, b0); MFMA128(acc[0][1], a0, b1);                   \
    MFMA128(acc[0][2], a0, b2); MFMA128(acc[0][3], a0, b3);                   \
    MFMA128(acc[1][0], a1, b0); MFMA128(acc[1][1], a1, b1);                   \
    MFMA128(acc[1][2], a1, b2); MFMA128(acc[1][3], a1, b3);                   \
    __builtin_amdgcn_s_setprio(0);                                            \
    i32x8v a2, a3;                                                            \
    MK8(a2, panA + rowA + 2048);   MK8(a3, panA + rowA + 3072);               \
    __builtin_amdgcn_s_setprio(1);                                            \
    MFMA128(acc[2][0], a2, b0); MFMA128(acc[2][1], a2, b1);                   \
    MFMA128(acc[2][2], a2, b2); MFMA128(acc[2][3], a2, b3);                   \
    MFMA128(acc[3][0], a3, b0); MFMA128(acc[3][1], a3, b1);                   \
    MFMA128(acc[3][2], a3, b2); MFMA128(acc[3][3], a3, b3);                   \
    __builtin_amdgcn_s_setprio(0);                                            \
    __builtin_amdgcn_sched_barrier(0);                                        \
    __builtin_amdgcn_s_barrier();                                             \
  } while (0)

  // prologue: stage K-tile 0 into slot 0 (6 loads in flight)
  STAGE6(0);

  // K-tiles 0..7; phase t stages t+1 into the other slot, gate vmcnt(6)
  QKV_PHASE(0, 6, 1);
  QKV_PHASE(1, 6, 1);
  QKV_PHASE(0, 6, 1);
  QKV_PHASE(1, 6, 1);
  QKV_PHASE(0, 6, 1);
  QKV_PHASE(1, 6, 1);
  QKV_PHASE(0, 6, 1);
  QKV_PHASE(1, 0, 0);

#undef QKV_PHASE
#undef MFMA128
#undef MK8
#undef STAGE6

  // epilogue (r9-verified): C row = base + (lane>>4)*4 + i, col = base + lr
  const int cr = lk4 << 2;
  const int z = bn >> 2;                       // 0=Q 1=K 2=V
  const int gr0 = bm * 128 + wm * 64;
  const int gc0 = (bn & 3) * 256 + wn * 64;
  if (z < 2) {
    unsigned short* C = (z == 0) ? Q : Kb;
#pragma unroll
    for (int m = 0; m < 4; ++m)
#pragma unroll
      for (int n = 0; n < 4; ++n)
#pragma unroll
        for (int i = 0; i < 4; ++i)
          C[(size_t)(gr0 + m * 16 + cr + i) * 1024 + (gc0 + n * 16 + lr)] =
              f32_to_bf16(acc[m][n][i]);
  } else {
    // Vt[b][d][t] = V[b*512+t][d]; 4 consecutive t per lane -> 8B store
#pragma unroll
    for (int m = 0; m < 4; ++m) {
      const int gr = gr0 + m * 16 + cr;
      const int b = gr >> 9, tt = gr & 511;
#pragma unroll
      for (int n = 0; n < 4; ++n) {
        const int d = gc0 + n * 16 + lr;
        US4 u;
        u.s[0] = f32_to_bf16(acc[m][n][0]);
        u.s[1] = f32_to_bf16(acc[m][n][1]);
        u.s[2] = f32_to_bf16(acc[m][n][2]);
        u.s[3] = f32_to_bf16(acc[m][n][3]);
        *(US4*)(Vt + ((size_t)b * 1024 + d) * 512 + tt) = u;
      }
    }
  }
}

// ---------------- shared BT-GEMM core (m97 structure + XOR swizzle) ----------
__device__ __forceinline__ void gemm_bt_core(const unsigned short* __restrict__ A,
                                             const unsigned short* __restrict__ B,
                                             int lda, int ldb, int K,
                                             unsigned short* As, unsigned short* Bs,
                                             f32x4 acc[4][4]) {
  const int tid = threadIdx.x;
  const int w = tid >> 6, lane = tid & 63;
  const int wr = w >> 1, wc = w & 1;
  const int lr = lane & 15;
  const int lk = (((lane >> 4) ^ ((lr >> 1) & 3))) << 3;
  const int k8 = (((lane & 3) ^ ((lane >> 3) & 3))) << 3;

  for (int kk = 0; kk < K; kk += 32) {
#pragma unroll
    for (int j = 0; j < 2; ++j) {
      const int i = (w << 1) + j;            // 0..7 wave-load id
      const int c = (i << 6) + lane;         // 16B chunk id, 512 per tile
      const int r = c >> 2;                  // tile row 0..127
      gload_lds16(A + (size_t)r * lda + kk + k8, As + (i << 9));
      gload_lds16(B + (size_t)r * ldb + kk + k8, Bs + (i << 9));
    }
    __syncthreads();                         // drains vmcnt for all waves
    bf16x8 av[4], bv[4];
#pragma unroll
    for (int m = 0; m < 4; ++m)
      av[m] = *(const bf16x8*)(As + (((wr << 6) + (m << 4) + lr) << 5) + lk);
#pragma unroll
    for (int n = 0; n < 4; ++n)
      bv[n] = *(const bf16x8*)(Bs + (((wc << 6) + (n << 4) + lr) << 5) + lk);
#pragma unroll
    for (int m = 0; m < 4; ++m)
#pragma unroll
      for (int n = 0; n < 4; ++n)
        acc[m][n] = __builtin_amdgcn_mfma_f32_16x16x32_bf16(av[m], bv[n], acc[m][n], 0, 0, 0);
    __syncthreads();
  }
}

// ---------------- S = Q K^T per batch (bf16 out) ----------------
__global__ __launch_bounds__(256) void s_gemm(const unsigned short* __restrict__ Q,
                                              const unsigned short* __restrict__ Kb,
                                              unsigned short* __restrict__ S) {
  __shared__ unsigned short As[4096];
  __shared__ unsigned short Bs[4096];
  const int bn = blockIdx.x, bm = blockIdx.y, b = blockIdx.z;
  const unsigned short* A = Q + ((size_t)b * 512 + bm * 128) * 1024;
  const unsigned short* B = Kb + ((size_t)b * 512 + bn * 128) * 1024;
  f32x4 acc[4][4] = {};
  gemm_bt_core(A, B, 1024, 1024, 1024, As, Bs, acc);

  const int tid = threadIdx.x;
  const int w = tid >> 6, lane = tid & 63;
  const int wr = w >> 1, wc = w & 1;
  const int cr = (lane >> 4) << 2;
  const int cc = lane & 15;
  unsigned short* Cp = S + (size_t)b * 262144;
  const int rbase = bm * 128 + wr * 64;
  const int cbase = bn * 128 + wc * 64;
#pragma unroll
  for (int m = 0; m < 4; ++m)
#pragma unroll
    for (int n = 0; n < 4; ++n)
#pragma unroll
      for (int i = 0; i < 4; ++i)
        Cp[(size_t)(rbase + m * 16 + cr + i) * 512 + (cbase + n * 16 + cc)] =
            f32_to_bf16(acc[m][n][i]);
}

// ---------------- row L2-normalize + softmax; write attn f32 + P bf16 -------
__global__ __launch_bounds__(256) void softmax_rows(const unsigned short* __restrict__ S,
                                                    float* __restrict__ out,
                                                    unsigned short* __restrict__ P) {
  const int w = threadIdx.x >> 6, lane = threadIdx.x & 63;
  const int r = blockIdx.x * 4 + w;          // global row 0..16383
  const int b = r >> 9, s = r & 511;
  US8 v = *(const US8*)(S + (size_t)r * 512 + lane * 8);
  float x[8];
#pragma unroll
  for (int i = 0; i < 8; ++i) x[i] = bf16_to_f32(v.s[i]);
  float ss = 0.f;
#pragma unroll
  for (int i = 0; i < 8; ++i) ss += x[i] * x[i];
  ss = wave_sum(ss);
  const float inv = 1.0f / fmaxf(sqrtf(ss), 1e-12f);
  float mx = -1e30f;
#pragma unroll
  for (int i = 0; i < 8; ++i) { x[i] *= inv; mx = fmaxf(mx, x[i]); }
  mx = wave_max(mx);
  float se = 0.f;
#pragma unroll
  for (int i = 0; i < 8; ++i) { x[i] = __expf(x[i] - mx); se += x[i]; }
  se = wave_sum(se);
  const float rs = 1.0f / se;
#pragma unroll
  for (int i = 0; i < 8; ++i) x[i] *= rs;

  float* op = out + (size_t)b * 786432 + 524288 + (size_t)s * 512 + lane * 8;
  float4 o0 = {x[0], x[1], x[2], x[3]};
  float4 o1 = {x[4], x[5], x[6], x[7]};
  *(float4*)op = o0;
  *(float4*)(op + 4) = o1;
  US8 u;
#pragma unroll
  for (int i = 0; i < 8; ++i) u.s[i] = f32_to_bf16(x[i]);
  *(US8*)(P + (size_t)r * 512 + lane * 8) = u;
}

// ---------------- O = P * V (via Vt, BT layout), bf16 out ----------------
__global__ __launch_bounds__(256) void pv_gemm(const unsigned short* __restrict__ P,
                                               const unsigned short* __restrict__ Vt,
                                               unsigned short* __restrict__ O) {
  __shared__ unsigned short As[4096];
  __shared__ unsigned short Bs[4096];
  const int bn = blockIdx.x, bm = blockIdx.y, b = blockIdx.z;
  const unsigned short* A = P + ((size_t)b * 512 + bm * 128) * 512;
  const unsigned short* B = Vt + ((size_t)b * 1024 + bn * 128) * 512;
  f32x4 acc[4][4] = {};
  gemm_bt_core(A, B, 512, 512, 512, As, Bs, acc);

  const int tid = threadIdx.x;
  const int w = tid >> 6, lane = tid & 63;
  const int wr = w >> 1, wc = w & 1;
  const int cr = (lane >> 4) << 2;
  const int cc = lane & 15;
  const int grow = b * 512 + bm * 128 + wr * 64;
  const int cbase = bn * 128 + wc * 64;
#pragma unroll
  for (int m = 0; m < 4; ++m)
#pragma unroll
    for (int n = 0; n < 4; ++n)
#pragma unroll
      for (int i = 0; i < 4; ++i)
        O[(size_t)(grow + m * 16 + cr + i) * 1024 + (cbase + n * 16 + cc)] =
            f32_to_bf16(acc[m][n][i]);
}

// ---------------- residual + LayerNorm, wave per row ----------------
__global__ __launch_bounds__(256) void ln_rows(const unsigned short* __restrict__ O,
                                               const unsigned short* __restrict__ Xb,
                                               const float* __restrict__ gamma,
                                               const float* __restrict__ beta,
                                               float* __restrict__ out) {
  const int w = threadIdx.x >> 6, lane = threadIdx.x & 63;
  const int r = blockIdx.x * 4 + w;
  const int b = r >> 9, s = r & 511;
  const unsigned short* orow = O + (size_t)r * 1024;
  const unsigned short* drow = Xb + (size_t)r * 1024;
  float x[16];
  float sm = 0.f, sq = 0.f;
#pragma unroll
  for (int j = 0; j < 4; ++j) {
    const int col = j * 256 + lane * 4;
    US4 o4 = *(const US4*)(orow + col);
    US4 d4 = *(const US4*)(drow + col);
    x[j * 4 + 0] = bf16_to_f32(o4.s[0]) + bf16_to_f32(d4.s[0]);
    x[j * 4 + 1] = bf16_to_f32(o4.s[1]) + bf16_to_f32(d4.s[1]);
    x[j * 4 + 2] = bf16_to_f32(o4.s[2]) + bf16_to_f32(d4.s[2]);
    x[j * 4 + 3] = bf16_to_f32(o4.s[3]) + bf16_to_f32(d4.s[3]);
  }
#pragma unroll
  for (int i = 0; i < 16; ++i) { sm += x[i]; sq += x[i] * x[i]; }
  sm = wave_sum(sm);
  sq = wave_sum(sq);
  const float mean = sm * (1.0f / 1024.0f);
  const float var = sq * (1.0f / 1024.0f) - mean * mean;
  const float rstd = rsqrtf(var + 1e-6f);
  float* op = out + (size_t)b * 786432 + (size_t)s * 1024;
#pragma unroll
  for (int j = 0; j < 4; ++j) {
    const int col = j * 256 + lane * 4;
    float4 g4 = *(const float4*)(gamma + col);
    float4 b4 = *(const float4*)(beta + col);
    float4 y;
    y.x = (x[j * 4 + 0] - mean) * rstd * g4.x + b4.x;
    y.y = (x[j * 4 + 1] - mean) * rstd * g4.y + b4.y;
    y.z = (x[j * 4 + 2] - mean) * rstd * g4.z + b4.z;
    y.w = (x[j * 4 + 3] - mean) * rstd * g4.w + b4.w;
    *(float4*)(op + col) = y;
  }
}

extern "C" void kernel_launch(void* const* d_in, const int* in_sizes, int n_in,
                              void* d_out, int out_size, void* d_ws, size_t ws_size,
                              hipStream_t stream) {
  const float* data  = (const float*)d_in[0];
  const float* wq    = (const float*)d_in[1];
  const float* wk    = (const float*)d_in[2];
  const float* wv    = (const float*)d_in[3];
  const float* gamma = (const float*)d_in[4];
  const float* beta  = (const float*)d_in[5];
  float* out = (float*)d_out;
  char* ws = (char*)d_ws;
  if (ws_size < WS_NEED) return;

  unsigned short* Xb = (unsigned short*)(ws + WS_XB);
  unsigned int*  Xf8 = (unsigned int*)(ws + WS_XF8);
  unsigned int*  Wf8 = (unsigned int*)(ws + WS_WF8);
  unsigned short* Q  = (unsigned short*)(ws + WS_Q);
  unsigned short* Kb = (unsigned short*)(ws + WS_K);
  unsigned short* Vt = (unsigned short*)(ws + WS_VT);
  unsigned short* S  = (unsigned short*)(ws + WS_S);
  unsigned short* P  = (unsigned short*)(ws + WS_P);
  unsigned short* O  = (unsigned short*)(ws + WS_O);

  cvt_data<<<8192, 256, 0, stream>>>(data, Xb, Xf8, 2097152);
  cvt_w3<<<dim3(512, 3), 256, 0, stream>>>(wq, wk, wv, Wf8);
  qkv_k128<<<1536, 512, 0, stream>>>((const unsigned char*)Xf8,
                                     (const unsigned char*)Wf8, Q, Kb, Vt);
  s_gemm<<<dim3(4, 4, 32), 256, 0, stream>>>(Q, Kb, S);
  softmax_rows<<<4096, 256, 0, stream>>>(S, out, P);
  pv_gemm<<<dim3(8, 4, 32), 256, 0, stream>>>(P, Vt, O);
  ln_rows<<<4096, 256, 0, stream>>>(O, Xb, gamma, beta, out);
}

// Round 14
// 183.255 us; speedup vs baseline: 1.3303x; 1.1948x over previous
//
#include <hip/hip_runtime.h>
#include <hip/hip_bf16.h>

// ModalAttention fused pipeline, MI355X (gfx950).
//
// Math: attn/|global_min| followed by L2-normalize cancels any positive
// per-tensor scale (incl. /sqrt(h)) -> softmax input = s_row/||s_row||_2,
// s = q.k. No global-min reduction needed.
//
// Round 14: round-13 bundle with the workspace-layout bug fixed: Vt8 is
// [32][1024][512] fp8 = 16.78MB (r13 allotted 8.39MB, so S overlapped
// Vt8's upper half -> s_f8's writes clobbered V for batches >=16 -> fp8
// NaN bytes -> NaN output). All region sizes re-derived and disjoint.
// The r12-proven fp8 K=128 GEMM core (128x256 tile, 2-slot 48KB, 6
// staging loads/K-tile, vmcnt(6), panel layout + 64B-row swizzle) drives
// all three GEMMs; Q/K/Vt stored fp8; P stored fp8 x256 (unscaled in pv).

typedef float f32x4 __attribute__((ext_vector_type(4)));
typedef int i32x4v __attribute__((ext_vector_type(4)));
typedef int i32x8v __attribute__((ext_vector_type(8)));

struct alignas(16) US8 { unsigned short s[8]; };
struct alignas(8)  US4 { unsigned short s[4]; };

// ---------------- workspace layout (bytes, disjoint) ----------------
#define WS_XB   0ull                        // data bf16 [16384][1024] 33.55MB
#define WS_XF8  33554432ull                 // data fp8  [16384][1024] 16.78MB
#define WS_WF8  50331648ull                 // wq,wk,wv fp8 [3][1024][1024] 3.15MB
#define WS_QF8  53477376ull                 // Q fp8 [16384][1024] 16.78MB
#define WS_KF8  70254592ull                 // K fp8 [16384][1024] 16.78MB
#define WS_VT8  87031808ull                 // V^T fp8 [32][1024][512] 16.78MB
#define WS_S    103809024ull                // S bf16 [16384][512] 16.78MB
#define WS_P8   120586240ull                // P fp8 (x256) [16384][512] 8.39MB
#define WS_O    128974848ull                // O bf16 [16384][1024] 33.55MB
#define WS_NEED 162529280ull

__device__ __forceinline__ unsigned short f32_to_bf16(float f) {
  unsigned int u = __builtin_bit_cast(unsigned int, f);
  u += 0x7fffu + ((u >> 16) & 1u);            // round-to-nearest-even
  return (unsigned short)(u >> 16);
}
__device__ __forceinline__ float bf16_to_f32(unsigned short h) {
  return __builtin_bit_cast(float, (unsigned int)h << 16);
}

__device__ __forceinline__ void gload_lds16(const void* g, void* lds) {
  __builtin_amdgcn_global_load_lds(
      (const __attribute__((address_space(1))) unsigned int*)g,
      (__attribute__((address_space(3))) unsigned int*)lds, 16, 0, 0);
}

__device__ __forceinline__ float wave_sum(float v) {
#pragma unroll
  for (int off = 32; off > 0; off >>= 1) v += __shfl_xor(v, off);
  return v;
}
__device__ __forceinline__ float wave_max(float v) {
#pragma unroll
  for (int off = 32; off > 0; off >>= 1) v = fmaxf(v, __shfl_xor(v, off));
  return v;
}

__device__ __forceinline__ unsigned int pk_fp8x4(float a, float b, float c, float d) {
  unsigned int v = 0;
  v = __builtin_amdgcn_cvt_pk_fp8_f32(a, b, v, false);  // bytes 0,1
  v = __builtin_amdgcn_cvt_pk_fp8_f32(c, d, v, true);   // bytes 2,3
  return v;
}
__device__ __forceinline__ unsigned char f32_to_fp8(float v) {
  return (unsigned char)(__builtin_amdgcn_cvt_pk_fp8_f32(v, v, 0, false) & 0xffu);
}

// ---------------- data cast: f32 -> bf16 (Xb) + fp8 (Xf8) ----------------
__global__ __launch_bounds__(256) void cvt_data(const float* __restrict__ src,
                                                unsigned short* __restrict__ dstb,
                                                unsigned int* __restrict__ dst8,
                                                int n8) {
  int i = blockIdx.x * 256 + threadIdx.x;
  if (i >= n8) return;
  const float4* sp = (const float4*)(src + (size_t)i * 8);
  float4 a = sp[0], b = sp[1];
  US8 u;
  u.s[0] = f32_to_bf16(a.x); u.s[1] = f32_to_bf16(a.y);
  u.s[2] = f32_to_bf16(a.z); u.s[3] = f32_to_bf16(a.w);
  u.s[4] = f32_to_bf16(b.x); u.s[5] = f32_to_bf16(b.y);
  u.s[6] = f32_to_bf16(b.z); u.s[7] = f32_to_bf16(b.w);
  *(US8*)(dstb + (size_t)i * 8) = u;
  uint2 w;
  w.x = pk_fp8x4(a.x, a.y, a.z, a.w);
  w.y = pk_fp8x4(b.x, b.y, b.z, b.w);
  *(uint2*)(dst8 + (size_t)i * 2) = w;
}

// ---------------- weights cast: f32 -> fp8, 3 matrices, one launch -------
__global__ __launch_bounds__(256) void cvt_w3(const float* __restrict__ wq,
                                              const float* __restrict__ wk,
                                              const float* __restrict__ wv,
                                              unsigned int* __restrict__ dst8) {
  const int z = blockIdx.y;
  const float* src = (z == 0) ? wq : (z == 1) ? wk : wv;
  int i = blockIdx.x * 256 + threadIdx.x;   // 0..131071 (x8 elems)
  const float4* sp = (const float4*)(src + (size_t)i * 8);
  float4 a = sp[0], b = sp[1];
  uint2 w;
  w.x = pk_fp8x4(a.x, a.y, a.z, a.w);
  w.y = pk_fp8x4(b.x, b.y, b.z, b.w);
  *(uint2*)(dst8 + (size_t)z * 262144 + (size_t)i * 2) = w;
}

// ============ shared fp8 K=128 GEMM core (r12-proven) ============
// C tile 128x256, 8 waves (wm=w>>2 row-half of 64, wn=w&3 col-quarter),
// per-wave 64x64 -> acc[4][4]. K-tiles of 128 fp8 bytes, NKT tiles.
// LDS slot (48KB): Ap0[0,8K) Ap1[8K,16K) Bp0[16K,32K) Bp1[32K,48K);
// panels are 64B rows, swizzle chunk^((row>>1)&3) (r12 formula).
template <int KB, int NKT>
__device__ __forceinline__ void f8_core(const char* __restrict__ Ag,
                                        const char* __restrict__ Bg,
                                        char* lds, f32x4 (&acc)[4][4]) {
  const int tid = threadIdx.x;
  const int w = tid >> 6, lane = tid & 63;
  const int wm = w >> 2, wn = w & 3;
  const int lr = lane & 15, lk4 = lane >> 4;

  const int sc = ((tid & 3) ^ ((tid >> 3) & 3)) * 16;
  const char* pA = Ag + (size_t)(tid >> 2) * KB + sc;
  const char* pB = Bg + (size_t)(tid >> 2) * KB + sc;
  const size_t BHALF = (size_t)128 * KB;

  const int swz = (lr >> 1) & 3;
  const int c0 = (lk4 & 1) * 2;
  const int cb0 = ((c0) ^ swz) * 16;
  const int cb1 = ((c0 + 1) ^ swz) * 16;
  const int panA = (lk4 >> 1) * 8192;
  const int panB = 16384 + (lk4 >> 1) * 16384;
  const int rowA = (wm * 64 + lr) * 64;
  const int rowB = (wn * 64 + lr) * 64;

#define STAGE6(DD)                                                            \
  do {                                                                        \
    char* dd_ = (DD);                                                         \
    gload_lds16(pA,              dd_ + tid * 16);                             \
    gload_lds16(pA + 64,         dd_ + 8192 + tid * 16);                      \
    gload_lds16(pB,              dd_ + 16384 + tid * 16);                     \
    gload_lds16(pB + BHALF,      dd_ + 24576 + tid * 16);                     \
    gload_lds16(pB + 64,         dd_ + 32768 + tid * 16);                     \
    gload_lds16(pB + BHALF + 64, dd_ + 40960 + tid * 16);                     \
    pA += 128; pB += 128;                                                     \
  } while (0)

#define MK8(D, OFF)                                                           \
  do {                                                                        \
    i32x4v lo_ = *(const i32x4v*)(sp + (OFF) + cb0);                          \
    i32x4v hi_ = *(const i32x4v*)(sp + (OFF) + cb1);                          \
    D[0] = lo_[0]; D[1] = lo_[1]; D[2] = lo_[2]; D[3] = lo_[3];               \
    D[4] = hi_[0]; D[5] = hi_[1]; D[6] = hi_[2]; D[7] = hi_[3];               \
  } while (0)

#define MFMA128(ACC, AV, BV)                                                  \
  asm("v_mfma_f32_16x16x128_f8f6f4 %0, %1, %2, %0"                            \
      : "+a"(ACC) : "v"(AV), "v"(BV))

  STAGE6(lds);   // prologue: K-tile 0 -> slot 0

#pragma unroll
  for (int t = 0; t < NKT; ++t) {
    const int slot = t & 1;
    if (t + 1 < NKT) {
      STAGE6(lds + (slot ^ 1) * 49152);
      asm volatile("s_waitcnt vmcnt(6)" ::: "memory");
    } else {
      asm volatile("s_waitcnt vmcnt(0)" ::: "memory");
    }
    __builtin_amdgcn_s_barrier();
    __builtin_amdgcn_sched_barrier(0);
    const char* sp = lds + slot * 49152;
    i32x8v a0, a1, b0, b1, b2, b3;
    MK8(a0, panA + rowA);          MK8(a1, panA + rowA + 1024);
    MK8(b0, panB + rowB);          MK8(b1, panB + rowB + 1024);
    MK8(b2, panB + rowB + 2048);   MK8(b3, panB + rowB + 3072);
    __builtin_amdgcn_s_setprio(1);
    MFMA128(acc[0][0], a0, b0); MFMA128(acc[0][1], a0, b1);
    MFMA128(acc[0][2], a0, b2); MFMA128(acc[0][3], a0, b3);
    MFMA128(acc[1][0], a1, b0); MFMA128(acc[1][1], a1, b1);
    MFMA128(acc[1][2], a1, b2); MFMA128(acc[1][3], a1, b3);
    __builtin_amdgcn_s_setprio(0);
    i32x8v a2, a3;
    MK8(a2, panA + rowA + 2048);   MK8(a3, panA + rowA + 3072);
    __builtin_amdgcn_s_setprio(1);
    MFMA128(acc[2][0], a2, b0); MFMA128(acc[2][1], a2, b1);
    MFMA128(acc[2][2], a2, b2); MFMA128(acc[2][3], a2, b3);
    MFMA128(acc[3][0], a3, b0); MFMA128(acc[3][1], a3, b1);
    MFMA128(acc[3][2], a3, b2); MFMA128(acc[3][3], a3, b3);
    __builtin_amdgcn_s_setprio(0);
    __builtin_amdgcn_sched_barrier(0);
    __builtin_amdgcn_s_barrier();
  }

#undef MFMA128
#undef MK8
#undef STAGE6
}

// ============ QKV: fp8 in, fp8 out (Q,K row-major; Vt transposed) ========
__global__ __launch_bounds__(512, 2) void qkv_k128(
    const unsigned char* __restrict__ Xf8, const unsigned char* __restrict__ Wf8,
    unsigned char* __restrict__ Qf8, unsigned char* __restrict__ Kf8,
    unsigned char* __restrict__ Vt8) {
  __shared__ alignas(16) char smc[2][49152];
  const int bid = blockIdx.x;
  const int wg = (bid & 7) * 192 + (bid >> 3);   // bijective XCD swizzle, 1536
  const int bm = wg / 12, bn = wg % 12;
  const char* Ag = (const char*)Xf8 + (size_t)bm * 128 * 1024;
  const char* Bg = (const char*)Wf8 + (size_t)bn * 256 * 1024;
  f32x4 acc[4][4] = {};
  f8_core<1024, 8>(Ag, Bg, &smc[0][0], acc);

  const int tid = threadIdx.x;
  const int w = tid >> 6, lane = tid & 63;
  const int wm = w >> 2, wn = w & 3;
  const int lr = lane & 15, lk4 = lane >> 4;
  const int cr = lk4 << 2;
  const int z = bn >> 2;                       // 0=Q 1=K 2=V
  const int gr0 = bm * 128 + wm * 64;
  const int gc0 = (bn & 3) * 256 + wn * 64;
  if (z < 2) {
    unsigned char* C = (z == 0) ? Qf8 : Kf8;
#pragma unroll
    for (int m = 0; m < 4; ++m)
#pragma unroll
      for (int n = 0; n < 4; ++n)
#pragma unroll
        for (int i = 0; i < 4; ++i)
          C[(size_t)(gr0 + m * 16 + cr + i) * 1024 + (gc0 + n * 16 + lr)] =
              f32_to_fp8(acc[m][n][i]);
  } else {
    // Vt8[b][d][t] = V[b*512+t][d]; 4 consecutive t -> one uint store
#pragma unroll
    for (int m = 0; m < 4; ++m) {
      const int gr = gr0 + m * 16 + cr;
      const int b = gr >> 9, tt = gr & 511;
#pragma unroll
      for (int n = 0; n < 4; ++n) {
        const int d = gc0 + n * 16 + lr;
        unsigned int u = pk_fp8x4(acc[m][n][0], acc[m][n][1],
                                  acc[m][n][2], acc[m][n][3]);
        *(unsigned int*)(Vt8 + ((size_t)b * 1024 + d) * 512 + tt) = u;
      }
    }
  }
}

// ============ S = Q K^T per batch (fp8 in, bf16 out) ============
__global__ __launch_bounds__(512, 2) void s_f8(
    const unsigned char* __restrict__ Qf8, const unsigned char* __restrict__ Kf8,
    unsigned short* __restrict__ S) {
  __shared__ alignas(16) char smc[2][49152];
  const int bn = blockIdx.x, bm = blockIdx.y, b = blockIdx.z;
  const char* Ag = (const char*)Qf8 + ((size_t)b * 512 + bm * 128) * 1024;
  const char* Bg = (const char*)Kf8 + ((size_t)b * 512 + bn * 256) * 1024;
  f32x4 acc[4][4] = {};
  f8_core<1024, 8>(Ag, Bg, &smc[0][0], acc);

  const int tid = threadIdx.x;
  const int w = tid >> 6, lane = tid & 63;
  const int wm = w >> 2, wn = w & 3;
  const int lr = lane & 15, lk4 = lane >> 4;
  const int cr = lk4 << 2;
  unsigned short* Cp = S + (size_t)b * 262144;
  const int rbase = bm * 128 + wm * 64;
  const int cbase = bn * 256 + wn * 64;
#pragma unroll
  for (int m = 0; m < 4; ++m)
#pragma unroll
    for (int n = 0; n < 4; ++n)
#pragma unroll
      for (int i = 0; i < 4; ++i)
        Cp[(size_t)(rbase + m * 16 + cr + i) * 512 + (cbase + n * 16 + lr)] =
            f32_to_bf16(acc[m][n][i]);
}

// -------- row L2-normalize + softmax; attn f32 out + P fp8 (x256) --------
__global__ __launch_bounds__(256) void softmax_rows(const unsigned short* __restrict__ S,
                                                    float* __restrict__ out,
                                                    unsigned char* __restrict__ P8) {
  const int w = threadIdx.x >> 6, lane = threadIdx.x & 63;
  const int r = blockIdx.x * 4 + w;          // global row 0..16383
  const int b = r >> 9, s = r & 511;
  US8 v = *(const US8*)(S + (size_t)r * 512 + lane * 8);
  float x[8];
#pragma unroll
  for (int i = 0; i < 8; ++i) x[i] = bf16_to_f32(v.s[i]);
  float ss = 0.f;
#pragma unroll
  for (int i = 0; i < 8; ++i) ss += x[i] * x[i];
  ss = wave_sum(ss);
  const float inv = 1.0f / fmaxf(sqrtf(ss), 1e-12f);
  float mx = -1e30f;
#pragma unroll
  for (int i = 0; i < 8; ++i) { x[i] *= inv; mx = fmaxf(mx, x[i]); }
  mx = wave_max(mx);
  float se = 0.f;
#pragma unroll
  for (int i = 0; i < 8; ++i) { x[i] = __expf(x[i] - mx); se += x[i]; }
  se = wave_sum(se);
  const float rs = 1.0f / se;
#pragma unroll
  for (int i = 0; i < 8; ++i) x[i] *= rs;

  float* op = out + (size_t)b * 786432 + 524288 + (size_t)s * 512 + lane * 8;
  float4 o0 = {x[0], x[1], x[2], x[3]};
  float4 o1 = {x[4], x[5], x[6], x[7]};
  *(float4*)op = o0;
  *(float4*)(op + 4) = o1;
  // P stored x256 (attn ~2e-3 is on e4m3's subnormal floor; x256 -> normal)
  uint2 pw;
  pw.x = pk_fp8x4(x[0] * 256.f, x[1] * 256.f, x[2] * 256.f, x[3] * 256.f);
  pw.y = pk_fp8x4(x[4] * 256.f, x[5] * 256.f, x[6] * 256.f, x[7] * 256.f);
  *(uint2*)(P8 + (size_t)r * 512 + lane * 8) = pw;
}

// ============ O = P V via Vt (fp8 in, bf16 out, 1/256 unscale) ============
__global__ __launch_bounds__(512, 2) void pv_f8(
    const unsigned char* __restrict__ P8, const unsigned char* __restrict__ Vt8,
    unsigned short* __restrict__ O) {
  __shared__ alignas(16) char smc[2][49152];
  const int bn = blockIdx.x, bm = blockIdx.y, b = blockIdx.z;
  const char* Ag = (const char*)P8 + ((size_t)b * 512 + bm * 128) * 512;
  const char* Bg = (const char*)Vt8 + ((size_t)b * 1024 + bn * 256) * 512;
  f32x4 acc[4][4] = {};
  f8_core<512, 4>(Ag, Bg, &smc[0][0], acc);

  const int tid = threadIdx.x;
  const int w = tid >> 6, lane = tid & 63;
  const int wm = w >> 2, wn = w & 3;
  const int lr = lane & 15, lk4 = lane >> 4;
  const int cr = lk4 << 2;
  const int grow = b * 512 + bm * 128 + wm * 64;
  const int cbase = bn * 256 + wn * 64;
#pragma unroll
  for (int m = 0; m < 4; ++m)
#pragma unroll
    for (int n = 0; n < 4; ++n)
#pragma unroll
      for (int i = 0; i < 4; ++i)
        O[(size_t)(grow + m * 16 + cr + i) * 1024 + (cbase + n * 16 + lr)] =
            f32_to_bf16(acc[m][n][i] * 0.00390625f);
}

// ---------------- residual + LayerNorm, wave per row ----------------
__global__ __launch_bounds__(256) void ln_rows(const unsigned short* __restrict__ O,
                                               const unsigned short* __restrict__ Xb,
                                               const float* __restrict__ gamma,
                                               const float* __restrict__ beta,
                                               float* __restrict__ out) {
  const int w = threadIdx.x >> 6, lane = threadIdx.x & 63;
  const int r = blockIdx.x * 4 + w;
  const int b = r >> 9, s = r & 511;
  const unsigned short* orow = O + (size_t)r * 1024;
  const unsigned short* drow = Xb + (size_t)r * 1024;
  float x[16];
  float sm = 0.f, sq = 0.f;
#pragma unroll
  for (int j = 0; j < 4; ++j) {
    const int col = j * 256 + lane * 4;
    US4 o4 = *(const US4*)(orow + col);
    US4 d4 = *(const US4*)(drow + col);
    x[j * 4 + 0] = bf16_to_f32(o4.s[0]) + bf16_to_f32(d4.s[0]);
    x[j * 4 + 1] = bf16_to_f32(o4.s[1]) + bf16_to_f32(d4.s[1]);
    x[j * 4 + 2] = bf16_to_f32(o4.s[2]) + bf16_to_f32(d4.s[2]);
    x[j * 4 + 3] = bf16_to_f32(o4.s[3]) + bf16_to_f32(d4.s[3]);
  }
#pragma unroll
  for (int i = 0; i < 16; ++i) { sm += x[i]; sq += x[i] * x[i]; }
  sm = wave_sum(sm);
  sq = wave_sum(sq);
  const float mean = sm * (1.0f / 1024.0f);
  const float var = sq * (1.0f / 1024.0f) - mean * mean;
  const float rstd = rsqrtf(var + 1e-6f);
  float* op = out + (size_t)b * 786432 + (size_t)s * 1024;
#pragma unroll
  for (int j = 0; j < 4; ++j) {
    const int col = j * 256 + lane * 4;
    float4 g4 = *(const float4*)(gamma + col);
    float4 b4 = *(const float4*)(beta + col);
    float4 y;
    y.x = (x[j * 4 + 0] - mean) * rstd * g4.x + b4.x;
    y.y = (x[j * 4 + 1] - mean) * rstd * g4.y + b4.y;
    y.z = (x[j * 4 + 2] - mean) * rstd * g4.z + b4.z;
    y.w = (x[j * 4 + 3] - mean) * rstd * g4.w + b4.w;
    *(float4*)(op + col) = y;
  }
}

extern "C" void kernel_launch(void* const* d_in, const int* in_sizes, int n_in,
                              void* d_out, int out_size, void* d_ws, size_t ws_size,
                              hipStream_t stream) {
  const float* data  = (const float*)d_in[0];
  const float* wq    = (const float*)d_in[1];
  const float* wk    = (const float*)d_in[2];
  const float* wv    = (const float*)d_in[3];
  const float* gamma = (const float*)d_in[4];
  const float* beta  = (const float*)d_in[5];
  float* out = (float*)d_out;
  char* ws = (char*)d_ws;
  if (ws_size < WS_NEED) return;

  unsigned short* Xb  = (unsigned short*)(ws + WS_XB);
  unsigned int*   Xf8 = (unsigned int*)(ws + WS_XF8);
  unsigned int*   Wf8 = (unsigned int*)(ws + WS_WF8);
  unsigned char*  Qf8 = (unsigned char*)(ws + WS_QF8);
  unsigned char*  Kf8 = (unsigned char*)(ws + WS_KF8);
  unsigned char*  Vt8 = (unsigned char*)(ws + WS_VT8);
  unsigned short* S   = (unsigned short*)(ws + WS_S);
  unsigned char*  P8  = (unsigned char*)(ws + WS_P8);
  unsigned short* O   = (unsigned short*)(ws + WS_O);

  cvt_data<<<8192, 256, 0, stream>>>(data, Xb, Xf8, 2097152);
  cvt_w3<<<dim3(512, 3), 256, 0, stream>>>(wq, wk, wv, Wf8);
  qkv_k128<<<1536, 512, 0, stream>>>((const unsigned char*)Xf8,
                                     (const unsigned char*)Wf8, Qf8, Kf8, Vt8);
  s_f8<<<dim3(2, 4, 32), 512, 0, stream>>>(Qf8, Kf8, S);
  softmax_rows<<<4096, 256, 0, stream>>>(S, out, P8);
  pv_f8<<<dim3(4, 4, 32), 512, 0, stream>>>(P8, Vt8, O);
  ln_rows<<<4096, 256, 0, stream>>>(O, Xb, gamma, beta, out);
}

// Round 15
// 163.656 us; speedup vs baseline: 1.4896x; 1.1198x over previous
//
#include <hip/hip_runtime.h>
#include <hip/hip_bf16.h>

// ModalAttention fused pipeline, MI355X (gfx950).
//
// Math: attn/|global_min| followed by L2-normalize cancels any positive
// per-tensor scale (incl. /sqrt(h)) -> softmax input = s_row/||s_row||_2,
// s = q.k. No global-min reduction needed.
//
// Round 15: the r12/r14-proven fp8 K=128 core shrunk to 128x128 tiles,
// 256 threads (4 waves, wm=w>>1, wn=w&1, per-wave 64x64), 2-slot LDS of
// 32KB -> 64KB total -> 2 BLOCKS/CU co-resident (cross-block TLP hides
// the barrier/vmcnt stalls; fp8 inputs are L3-resident so the extra
// operand re-fetch of smaller tiles is ~free). Same panel layout, same
// involution swizzle (staging row+64 keeps the per-lane XOR constant
// since 32=0 mod 4), same MFMA asm, same K order -> bit-exact vs r14.
// Drives all three GEMMs: qkv (3072 blocks, XCD-chunked), s (512), pv
// (1024). cvt/softmax/ln identical to round-14 passing code.

typedef float f32x4 __attribute__((ext_vector_type(4)));
typedef int i32x4v __attribute__((ext_vector_type(4)));
typedef int i32x8v __attribute__((ext_vector_type(8)));

struct alignas(16) US8 { unsigned short s[8]; };
struct alignas(8)  US4 { unsigned short s[4]; };

// ---------------- workspace layout (bytes, disjoint) ----------------
#define WS_XB   0ull                        // data bf16 [16384][1024] 33.55MB
#define WS_XF8  33554432ull                 // data fp8  [16384][1024] 16.78MB
#define WS_WF8  50331648ull                 // wq,wk,wv fp8 [3][1024][1024] 3.15MB
#define WS_QF8  53477376ull                 // Q fp8 [16384][1024] 16.78MB
#define WS_KF8  70254592ull                 // K fp8 [16384][1024] 16.78MB
#define WS_VT8  87031808ull                 // V^T fp8 [32][1024][512] 16.78MB
#define WS_S    103809024ull                // S bf16 [16384][512] 16.78MB
#define WS_P8   120586240ull                // P fp8 (x256) [16384][512] 8.39MB
#define WS_O    128974848ull                // O bf16 [16384][1024] 33.55MB
#define WS_NEED 162529280ull

__device__ __forceinline__ unsigned short f32_to_bf16(float f) {
  unsigned int u = __builtin_bit_cast(unsigned int, f);
  u += 0x7fffu + ((u >> 16) & 1u);            // round-to-nearest-even
  return (unsigned short)(u >> 16);
}
__device__ __forceinline__ float bf16_to_f32(unsigned short h) {
  return __builtin_bit_cast(float, (unsigned int)h << 16);
}

__device__ __forceinline__ void gload_lds16(const void* g, void* lds) {
  __builtin_amdgcn_global_load_lds(
      (const __attribute__((address_space(1))) unsigned int*)g,
      (__attribute__((address_space(3))) unsigned int*)lds, 16, 0, 0);
}

__device__ __forceinline__ float wave_sum(float v) {
#pragma unroll
  for (int off = 32; off > 0; off >>= 1) v += __shfl_xor(v, off);
  return v;
}
__device__ __forceinline__ float wave_max(float v) {
#pragma unroll
  for (int off = 32; off > 0; off >>= 1) v = fmaxf(v, __shfl_xor(v, off));
  return v;
}

__device__ __forceinline__ unsigned int pk_fp8x4(float a, float b, float c, float d) {
  unsigned int v = 0;
  v = __builtin_amdgcn_cvt_pk_fp8_f32(a, b, v, false);  // bytes 0,1
  v = __builtin_amdgcn_cvt_pk_fp8_f32(c, d, v, true);   // bytes 2,3
  return v;
}
__device__ __forceinline__ unsigned char f32_to_fp8(float v) {
  return (unsigned char)(__builtin_amdgcn_cvt_pk_fp8_f32(v, v, 0, false) & 0xffu);
}

// ---------------- data cast: f32 -> bf16 (Xb) + fp8 (Xf8) ----------------
__global__ __launch_bounds__(256) void cvt_data(const float* __restrict__ src,
                                                unsigned short* __restrict__ dstb,
                                                unsigned int* __restrict__ dst8,
                                                int n8) {
  int i = blockIdx.x * 256 + threadIdx.x;
  if (i >= n8) return;
  const float4* sp = (const float4*)(src + (size_t)i * 8);
  float4 a = sp[0], b = sp[1];
  US8 u;
  u.s[0] = f32_to_bf16(a.x); u.s[1] = f32_to_bf16(a.y);
  u.s[2] = f32_to_bf16(a.z); u.s[3] = f32_to_bf16(a.w);
  u.s[4] = f32_to_bf16(b.x); u.s[5] = f32_to_bf16(b.y);
  u.s[6] = f32_to_bf16(b.z); u.s[7] = f32_to_bf16(b.w);
  *(US8*)(dstb + (size_t)i * 8) = u;
  uint2 w;
  w.x = pk_fp8x4(a.x, a.y, a.z, a.w);
  w.y = pk_fp8x4(b.x, b.y, b.z, b.w);
  *(uint2*)(dst8 + (size_t)i * 2) = w;
}

// ---------------- weights cast: f32 -> fp8, 3 matrices, one launch -------
__global__ __launch_bounds__(256) void cvt_w3(const float* __restrict__ wq,
                                              const float* __restrict__ wk,
                                              const float* __restrict__ wv,
                                              unsigned int* __restrict__ dst8) {
  const int z = blockIdx.y;
  const float* src = (z == 0) ? wq : (z == 1) ? wk : wv;
  int i = blockIdx.x * 256 + threadIdx.x;   // 0..131071 (x8 elems)
  const float4* sp = (const float4*)(src + (size_t)i * 8);
  float4 a = sp[0], b = sp[1];
  uint2 w;
  w.x = pk_fp8x4(a.x, a.y, a.z, a.w);
  w.y = pk_fp8x4(b.x, b.y, b.z, b.w);
  *(uint2*)(dst8 + (size_t)z * 262144 + (size_t)i * 2) = w;
}

// ============ fp8 K=128 GEMM core, 128x128 tile, 256 threads ============
// 4 waves: wm=w>>1 (row-half of 64), wn=w&1 (col-half of 64); per-wave
// 64x64 -> acc[4][4]. K-tiles of 128 fp8 bytes, NKT tiles.
// LDS slot (32KB): Ap0[0,8K) Ap1[8K,16K) Bp0[16K,24K) Bp1[24K,32K);
// panels = 128 rows x 64B, swizzle chunk^((row>>1)&3) (r12-proven).
// Staging: 8 x 16B/thread (rows tid>>2 and +64 per region; +64 keeps the
// per-lane XOR constant since 32 = 0 mod 4). vmcnt(8) counted gate.
template <int KB, int NKT>
__device__ __forceinline__ void f8c128(const char* __restrict__ Ag,
                                       const char* __restrict__ Bg,
                                       char* lds, f32x4 (&acc)[4][4]) {
  const int tid = threadIdx.x;
  const int w = tid >> 6, lane = tid & 63;
  const int wm = w >> 1, wn = w & 1;
  const int lr = lane & 15, lk4 = lane >> 4;

  const int sc = ((tid & 3) ^ ((tid >> 3) & 3)) * 16;
  const char* pA = Ag + (size_t)(tid >> 2) * KB + sc;
  const char* pB = Bg + (size_t)(tid >> 2) * KB + sc;
  const size_t R64 = (size_t)64 * KB;

  const int swz = (lr >> 1) & 3;
  const int c0 = (lk4 & 1) * 2;
  const int cb0 = ((c0) ^ swz) * 16;
  const int cb1 = ((c0 + 1) ^ swz) * 16;
  const int panA = (lk4 >> 1) * 8192;
  const int panB = 16384 + (lk4 >> 1) * 8192;
  const int rowA = (wm * 64 + lr) * 64;
  const int rowB = (wn * 64 + lr) * 64;

#define STAGE8(DD)                                                            \
  do {                                                                        \
    char* dd_ = (DD);                                                         \
    gload_lds16(pA,            dd_ + tid * 16);                               \
    gload_lds16(pA + R64,      dd_ + 4096 + tid * 16);                        \
    gload_lds16(pA + 64,       dd_ + 8192 + tid * 16);                        \
    gload_lds16(pA + R64 + 64, dd_ + 12288 + tid * 16);                       \
    gload_lds16(pB,            dd_ + 16384 + tid * 16);                       \
    gload_lds16(pB + R64,      dd_ + 20480 + tid * 16);                       \
    gload_lds16(pB + 64,       dd_ + 24576 + tid * 16);                       \
    gload_lds16(pB + R64 + 64, dd_ + 28672 + tid * 16);                       \
    pA += 128; pB += 128;                                                     \
  } while (0)

#define MK8(D, OFF)                                                           \
  do {                                                                        \
    i32x4v lo_ = *(const i32x4v*)(sp + (OFF) + cb0);                          \
    i32x4v hi_ = *(const i32x4v*)(sp + (OFF) + cb1);                          \
    D[0] = lo_[0]; D[1] = lo_[1]; D[2] = lo_[2]; D[3] = lo_[3];               \
    D[4] = hi_[0]; D[5] = hi_[1]; D[6] = hi_[2]; D[7] = hi_[3];               \
  } while (0)

#define MFMA128(ACC, AV, BV)                                                  \
  asm("v_mfma_f32_16x16x128_f8f6f4 %0, %1, %2, %0"                            \
      : "+a"(ACC) : "v"(AV), "v"(BV))

  STAGE8(lds);   // prologue: K-tile 0 -> slot 0

#pragma unroll
  for (int t = 0; t < NKT; ++t) {
    const int slot = t & 1;
    if (t + 1 < NKT) {
      STAGE8(lds + (slot ^ 1) * 32768);
      asm volatile("s_waitcnt vmcnt(8)" ::: "memory");
    } else {
      asm volatile("s_waitcnt vmcnt(0)" ::: "memory");
    }
    __builtin_amdgcn_s_barrier();
    __builtin_amdgcn_sched_barrier(0);
    const char* sp = lds + slot * 32768;
    i32x8v a0, a1, b0, b1, b2, b3;
    MK8(a0, panA + rowA);          MK8(a1, panA + rowA + 1024);
    MK8(b0, panB + rowB);          MK8(b1, panB + rowB + 1024);
    MK8(b2, panB + rowB + 2048);   MK8(b3, panB + rowB + 3072);
    __builtin_amdgcn_s_setprio(1);
    MFMA128(acc[0][0], a0, b0); MFMA128(acc[0][1], a0, b1);
    MFMA128(acc[0][2], a0, b2); MFMA128(acc[0][3], a0, b3);
    MFMA128(acc[1][0], a1, b0); MFMA128(acc[1][1], a1, b1);
    MFMA128(acc[1][2], a1, b2); MFMA128(acc[1][3], a1, b3);
    __builtin_amdgcn_s_setprio(0);
    i32x8v a2, a3;
    MK8(a2, panA + rowA + 2048);   MK8(a3, panA + rowA + 3072);
    __builtin_amdgcn_s_setprio(1);
    MFMA128(acc[2][0], a2, b0); MFMA128(acc[2][1], a2, b1);
    MFMA128(acc[2][2], a2, b2); MFMA128(acc[2][3], a2, b3);
    MFMA128(acc[3][0], a3, b0); MFMA128(acc[3][1], a3, b1);
    MFMA128(acc[3][2], a3, b2); MFMA128(acc[3][3], a3, b3);
    __builtin_amdgcn_s_setprio(0);
    __builtin_amdgcn_sched_barrier(0);
    __builtin_amdgcn_s_barrier();
  }

#undef MFMA128
#undef MK8
#undef STAGE8
}

// ============ QKV: fp8 in, fp8 out (Q,K row-major; Vt transposed) ========
// Grid 3072 (128 M-tiles x 24 N-tiles), XCD-chunked: consecutive wg share
// bm -> A panel L2-local. 2 blocks/CU.
__global__ __launch_bounds__(256, 2) void qkv_128(
    const unsigned char* __restrict__ Xf8, const unsigned char* __restrict__ Wf8,
    unsigned char* __restrict__ Qf8, unsigned char* __restrict__ Kf8,
    unsigned char* __restrict__ Vt8) {
  __shared__ alignas(16) char smc[2][32768];
  const int bid = blockIdx.x;
  const int wg = (bid & 7) * 384 + (bid >> 3);   // bijective, 3072 % 8 == 0
  const int bm = wg / 24, bn = wg % 24;
  const char* Ag = (const char*)Xf8 + (size_t)bm * 128 * 1024;
  const char* Bg = (const char*)Wf8 + (size_t)bn * 128 * 1024;
  f32x4 acc[4][4] = {};
  f8c128<1024, 8>(Ag, Bg, &smc[0][0], acc);

  const int tid = threadIdx.x;
  const int w = tid >> 6, lane = tid & 63;
  const int wm = w >> 1, wn = w & 1;
  const int lr = lane & 15, lk4 = lane >> 4;
  const int cr = lk4 << 2;
  const int z = bn >> 3;                       // 0=Q 1=K 2=V
  const int gr0 = bm * 128 + wm * 64;
  const int gc0 = (bn & 7) * 128 + wn * 64;
  if (z < 2) {
    unsigned char* C = (z == 0) ? Qf8 : Kf8;
#pragma unroll
    for (int m = 0; m < 4; ++m)
#pragma unroll
      for (int n = 0; n < 4; ++n)
#pragma unroll
        for (int i = 0; i < 4; ++i)
          C[(size_t)(gr0 + m * 16 + cr + i) * 1024 + (gc0 + n * 16 + lr)] =
              f32_to_fp8(acc[m][n][i]);
  } else {
    // Vt8[b][d][t] = V[b*512+t][d]; 4 consecutive t -> one uint store
#pragma unroll
    for (int m = 0; m < 4; ++m) {
      const int gr = gr0 + m * 16 + cr;
      const int b = gr >> 9, tt = gr & 511;
#pragma unroll
      for (int n = 0; n < 4; ++n) {
        const int d = gc0 + n * 16 + lr;
        unsigned int u = pk_fp8x4(acc[m][n][0], acc[m][n][1],
                                  acc[m][n][2], acc[m][n][3]);
        *(unsigned int*)(Vt8 + ((size_t)b * 1024 + d) * 512 + tt) = u;
      }
    }
  }
}

// ============ S = Q K^T per batch (fp8 in, bf16 out) ============
__global__ __launch_bounds__(256, 2) void s_f8(
    const unsigned char* __restrict__ Qf8, const unsigned char* __restrict__ Kf8,
    unsigned short* __restrict__ S) {
  __shared__ alignas(16) char smc[2][32768];
  const int bn = blockIdx.x, bm = blockIdx.y, b = blockIdx.z;
  const char* Ag = (const char*)Qf8 + ((size_t)b * 512 + bm * 128) * 1024;
  const char* Bg = (const char*)Kf8 + ((size_t)b * 512 + bn * 128) * 1024;
  f32x4 acc[4][4] = {};
  f8c128<1024, 8>(Ag, Bg, &smc[0][0], acc);

  const int tid = threadIdx.x;
  const int w = tid >> 6, lane = tid & 63;
  const int wm = w >> 1, wn = w & 1;
  const int lr = lane & 15, lk4 = lane >> 4;
  const int cr = lk4 << 2;
  unsigned short* Cp = S + (size_t)b * 262144;
  const int rbase = bm * 128 + wm * 64;
  const int cbase = bn * 128 + wn * 64;
#pragma unroll
  for (int m = 0; m < 4; ++m)
#pragma unroll
    for (int n = 0; n < 4; ++n)
#pragma unroll
      for (int i = 0; i < 4; ++i)
        Cp[(size_t)(rbase + m * 16 + cr + i) * 512 + (cbase + n * 16 + lr)] =
            f32_to_bf16(acc[m][n][i]);
}

// -------- row L2-normalize + softmax; attn f32 out + P fp8 (x256) --------
__global__ __launch_bounds__(256) void softmax_rows(const unsigned short* __restrict__ S,
                                                    float* __restrict__ out,
                                                    unsigned char* __restrict__ P8) {
  const int w = threadIdx.x >> 6, lane = threadIdx.x & 63;
  const int r = blockIdx.x * 4 + w;          // global row 0..16383
  const int b = r >> 9, s = r & 511;
  US8 v = *(const US8*)(S + (size_t)r * 512 + lane * 8);
  float x[8];
#pragma unroll
  for (int i = 0; i < 8; ++i) x[i] = bf16_to_f32(v.s[i]);
  float ss = 0.f;
#pragma unroll
  for (int i = 0; i < 8; ++i) ss += x[i] * x[i];
  ss = wave_sum(ss);
  const float inv = 1.0f / fmaxf(sqrtf(ss), 1e-12f);
  float mx = -1e30f;
#pragma unroll
  for (int i = 0; i < 8; ++i) { x[i] *= inv; mx = fmaxf(mx, x[i]); }
  mx = wave_max(mx);
  float se = 0.f;
#pragma unroll
  for (int i = 0; i < 8; ++i) { x[i] = __expf(x[i] - mx); se += x[i]; }
  se = wave_sum(se);
  const float rs = 1.0f / se;
#pragma unroll
  for (int i = 0; i < 8; ++i) x[i] *= rs;

  float* op = out + (size_t)b * 786432 + 524288 + (size_t)s * 512 + lane * 8;
  float4 o0 = {x[0], x[1], x[2], x[3]};
  float4 o1 = {x[4], x[5], x[6], x[7]};
  *(float4*)op = o0;
  *(float4*)(op + 4) = o1;
  // P stored x256 (attn ~2e-3 is on e4m3's subnormal floor; x256 -> normal)
  uint2 pw;
  pw.x = pk_fp8x4(x[0] * 256.f, x[1] * 256.f, x[2] * 256.f, x[3] * 256.f);
  pw.y = pk_fp8x4(x[4] * 256.f, x[5] * 256.f, x[6] * 256.f, x[7] * 256.f);
  *(uint2*)(P8 + (size_t)r * 512 + lane * 8) = pw;
}

// ============ O = P V via Vt (fp8 in, bf16 out, 1/256 unscale) ============
__global__ __launch_bounds__(256, 2) void pv_f8(
    const unsigned char* __restrict__ P8, const unsigned char* __restrict__ Vt8,
    unsigned short* __restrict__ O) {
  __shared__ alignas(16) char smc[2][32768];
  const int bn = blockIdx.x, bm = blockIdx.y, b = blockIdx.z;
  const char* Ag = (const char*)P8 + ((size_t)b * 512 + bm * 128) * 512;
  const char* Bg = (const char*)Vt8 + ((size_t)b * 1024 + bn * 128) * 512;
  f32x4 acc[4][4] = {};
  f8c128<512, 4>(Ag, Bg, &smc[0][0], acc);

  const int tid = threadIdx.x;
  const int w = tid >> 6, lane = tid & 63;
  const int wm = w >> 1, wn = w & 1;
  const int lr = lane & 15, lk4 = lane >> 4;
  const int cr = lk4 << 2;
  const int grow = b * 512 + bm * 128 + wm * 64;
  const int cbase = bn * 128 + wn * 64;
#pragma unroll
  for (int m = 0; m < 4; ++m)
#pragma unroll
    for (int n = 0; n < 4; ++n)
#pragma unroll
      for (int i = 0; i < 4; ++i)
        O[(size_t)(grow + m * 16 + cr + i) * 1024 + (cbase + n * 16 + lr)] =
            f32_to_bf16(acc[m][n][i] * 0.00390625f);
}

// ---------------- residual + LayerNorm, wave per row ----------------
__global__ __launch_bounds__(256) void ln_rows(const unsigned short* __restrict__ O,
                                               const unsigned short* __restrict__ Xb,
                                               const float* __restrict__ gamma,
                                               const float* __restrict__ beta,
                                               float* __restrict__ out) {
  const int w = threadIdx.x >> 6, lane = threadIdx.x & 63;
  const int r = blockIdx.x * 4 + w;
  const int b = r >> 9, s = r & 511;
  const unsigned short* orow = O + (size_t)r * 1024;
  const unsigned short* drow = Xb + (size_t)r * 1024;
  float x[16];
  float sm = 0.f, sq = 0.f;
#pragma unroll
  for (int j = 0; j < 4; ++j) {
    const int col = j * 256 + lane * 4;
    US4 o4 = *(const US4*)(orow + col);
    US4 d4 = *(const US4*)(drow + col);
    x[j * 4 + 0] = bf16_to_f32(o4.s[0]) + bf16_to_f32(d4.s[0]);
    x[j * 4 + 1] = bf16_to_f32(o4.s[1]) + bf16_to_f32(d4.s[1]);
    x[j * 4 + 2] = bf16_to_f32(o4.s[2]) + bf16_to_f32(d4.s[2]);
    x[j * 4 + 3] = bf16_to_f32(o4.s[3]) + bf16_to_f32(d4.s[3]);
  }
#pragma unroll
  for (int i = 0; i < 16; ++i) { sm += x[i]; sq += x[i] * x[i]; }
  sm = wave_sum(sm);
  sq = wave_sum(sq);
  const float mean = sm * (1.0f / 1024.0f);
  const float var = sq * (1.0f / 1024.0f) - mean * mean;
  const float rstd = rsqrtf(var + 1e-6f);
  float* op = out + (size_t)b * 786432 + (size_t)s * 1024;
#pragma unroll
  for (int j = 0; j < 4; ++j) {
    const int col = j * 256 + lane * 4;
    float4 g4 = *(const float4*)(gamma + col);
    float4 b4 = *(const float4*)(beta + col);
    float4 y;
    y.x = (x[j * 4 + 0] - mean) * rstd * g4.x + b4.x;
    y.y = (x[j * 4 + 1] - mean) * rstd * g4.y + b4.y;
    y.z = (x[j * 4 + 2] - mean) * rstd * g4.z + b4.z;
    y.w = (x[j * 4 + 3] - mean) * rstd * g4.w + b4.w;
    *(float4*)(op + col) = y;
  }
}

extern "C" void kernel_launch(void* const* d_in, const int* in_sizes, int n_in,
                              void* d_out, int out_size, void* d_ws, size_t ws_size,
                              hipStream_t stream) {
  const float* data  = (const float*)d_in[0];
  const float* wq    = (const float*)d_in[1];
  const float* wk    = (const float*)d_in[2];
  const float* wv    = (const float*)d_in[3];
  const float* gamma = (const float*)d_in[4];
  const float* beta  = (const float*)d_in[5];
  float* out = (float*)d_out;
  char* ws = (char*)d_ws;
  if (ws_size < WS_NEED) return;

  unsigned short* Xb  = (unsigned short*)(ws + WS_XB);
  unsigned int*   Xf8 = (unsigned int*)(ws + WS_XF8);
  unsigned int*   Wf8 = (unsigned int*)(ws + WS_WF8);
  unsigned char*  Qf8 = (unsigned char*)(ws + WS_QF8);
  unsigned char*  Kf8 = (unsigned char*)(ws + WS_KF8);
  unsigned char*  Vt8 = (unsigned char*)(ws + WS_VT8);
  unsigned short* S   = (unsigned short*)(ws + WS_S);
  unsigned char*  P8  = (unsigned char*)(ws + WS_P8);
  unsigned short* O   = (unsigned short*)(ws + WS_O);

  cvt_data<<<8192, 256, 0, stream>>>(data, Xb, Xf8, 2097152);
  cvt_w3<<<dim3(512, 3), 256, 0, stream>>>(wq, wk, wv, Wf8);
  qkv_128<<<3072, 256, 0, stream>>>((const unsigned char*)Xf8,
                                    (const unsigned char*)Wf8, Qf8, Kf8, Vt8);
  s_f8<<<dim3(4, 4, 32), 256, 0, stream>>>(Qf8, Kf8, S);
  softmax_rows<<<4096, 256, 0, stream>>>(S, out, P8);
  pv_f8<<<dim3(8, 4, 32), 256, 0, stream>>>(P8, Vt8, O);
  ln_rows<<<4096, 256, 0, stream>>>(O, Xb, gamma, beta, out);
}